// Round 4
// baseline (99.291 us; speedup 1.0000x reference)
//
#include <hip/hip_runtime.h>

// LocalConvolutionMixMerge: per-pixel local conv, 3x3 + 5x5, weights shared
// across 8 channel groups (c % 32).
//
// R4: 4 pixels per thread (float4). Every global access (weights, x, out)
// becomes a 1 KB-contiguous wave transaction (64 lanes x 16 B spanning 4
// consecutive image rows) instead of scattered 256 B granules. Horizontal
// stencil taps via 16-lane DPP row shifts: 16 lanes x 4 px = one full 64-px
// image row per DPP row, so bound_ctrl zero-fill == the image's w-padding.

#define HW_ 4096
typedef float f4 __attribute__((ext_vector_type(4)));

__device__ __forceinline__ float row_shl1(float v) {  // lane i <- lane i+1 (16-lane row); 0 at row end
  return __builtin_bit_cast(
      float, __builtin_amdgcn_update_dpp(0, __builtin_bit_cast(int, v),
                                         0x101, 0xF, 0xF, true));
}
__device__ __forceinline__ float row_shr1(float v) {  // lane i <- lane i-1 (16-lane row); 0 at row start
  return __builtin_bit_cast(
      float, __builtin_amdgcn_update_dpp(0, __builtin_bit_cast(int, v),
                                         0x111, 0xF, 0xF, true));
}

__device__ __forceinline__ void fma4(f4& acc, f4 a, f4 b) {
  acc.x = fmaf(a.x, b.x, acc.x);
  acc.y = fmaf(a.y, b.y, acc.y);
  acc.z = fmaf(a.z, b.z, acc.z);
  acc.w = fmaf(a.w, b.w, acc.w);
}

__global__ __launch_bounds__(256, 1) void lconv_mix_kernel(
    const float* __restrict__ x, const float* __restrict__ wgt,
    float* __restrict__ out) {
  int idx = blockIdx.x * 256 + threadIdx.x;  // [N][WC=32][H=64][W/4=16]
  int h  = (idx >> 4) & 63;
  int wc = (idx >> 10) & 31;
  int n  = idx >> 15;
  int pix = (idx & 0x3FF) << 2;  // h*64 + w4 (flat pixel offset within a plane)

  // Weights: 34 float4 nontemporal loads; plane stride = 1024 f4.
  const f4* wb = (const f4*)(wgt + (size_t)n * 1088 * HW_ + pix);
  f4 w1[9], w2[25];
#pragma unroll
  for (int t = 0; t < 9; ++t)
    w1[t] = __builtin_nontemporal_load(&wb[(size_t)(wc * 9 + t) * 1024]);
#pragma unroll
  for (int t = 0; t < 25; ++t)
    w2[t] = __builtin_nontemporal_load(&wb[(size_t)(288 + wc * 25 + t) * 1024]);

  const float* xn = x + (size_t)n * 256 * HW_ + pix;
  float* o1 = out + ((size_t)(n * 2 + 0) * 256) * HW_ + pix;
  float* o2 = out + ((size_t)(n * 2 + 1) * 256) * HW_ + pix;

#pragma unroll
  for (int g = 0; g < 8; ++g) {
    int cc = g * 32 + wc;
    const f4* xc = (const f4*)(xn + (size_t)cc * HW_);

    f4 a1 = {0.f, 0.f, 0.f, 0.f}, a2 = {0.f, 0.f, 0.f, 0.f};
#pragma unroll
    for (int i = 0; i < 5; ++i) {
      int hh = h + i - 2;
      f4 v = {0.f, 0.f, 0.f, 0.f};
      if ((unsigned)hh < 64u) v = xc[(i - 2) * 16];

      // Horizontal neighbors: lane i holds px 4i..4i+3 of a 64-px row
      // spanned by its 16-lane DPP row.
      float lx = row_shr1(v.w);  // px-1 for component .x
      float lz = row_shr1(v.z);  // px-2 for component .x
      float rx = row_shl1(v.x);  // px+1 for component .w
      float ry = row_shl1(v.y);  // px+2 for component .w
      f4 m1 = {lx, v.x, v.y, v.z};   // value at px-1
      f4 m2 = {lz, lx, v.x, v.y};    // value at px-2
      f4 q1 = {v.y, v.z, v.w, rx};   // value at px+1
      f4 q2 = {v.z, v.w, rx, ry};    // value at px+2

      fma4(a2, m2, w2[i * 5 + 0]);
      fma4(a2, m1, w2[i * 5 + 1]);
      fma4(a2, v,  w2[i * 5 + 2]);
      fma4(a2, q1, w2[i * 5 + 3]);
      fma4(a2, q2, w2[i * 5 + 4]);

      if (i >= 1 && i <= 3) {  // inner 3x3 reuses the same shifted vectors
        fma4(a1, m1, w1[(i - 1) * 3 + 0]);
        fma4(a1, v,  w1[(i - 1) * 3 + 1]);
        fma4(a1, q1, w1[(i - 1) * 3 + 2]);
      }
    }

    __builtin_nontemporal_store(a1, (f4*)(o1 + (size_t)cc * HW_));
    __builtin_nontemporal_store(a2, (f4*)(o2 + (size_t)cc * HW_));
  }
}

extern "C" void kernel_launch(void* const* d_in, const int* in_sizes, int n_in,
                              void* d_out, int out_size, void* d_ws,
                              size_t ws_size, hipStream_t stream) {
  const float* x = (const float*)d_in[0];
  const float* wgt = (const float*)d_in[1];
  float* out = (float*)d_out;

  int total = 2 * 32 * 64 * 16;  // N * WC * H * (W/4) threads
  lconv_mix_kernel<<<dim3(total / 256), dim3(256), 0, stream>>>(x, wgt, out);
}

// Round 5
// 92.350 us; speedup vs baseline: 1.0752x; 1.0752x over previous
//
#include <hip/hip_runtime.h>

// LocalConvolutionMixMerge: per-pixel local convolution with 3x3 and 5x5
// kernels whose weights are shared across 8 channel groups (c % 32).
//
// R5: exact revert to the R1 kernel — best measured variant (92.1 µs).
// Empirical record: DPP horizontal taps (R2, 93.0), k-split occupancy
// doubling (R3, 97.4), float4 granularity (R4, 99.3) all regressed.
// One thread per (n, wc, h, w), looping over 8 channel groups so the 34
// per-pixel weights are loaded once and reused 8x; all accesses coalesced
// (lanes -> consecutive w). Kernel I/O floor: 61 MB ≈ 10 µs; kernel is
// <42 µs (below harness fill dispatches in rocprof), dur_us dominated by
// ~75 µs of harness restore/poison traffic.

#define HW_ (64 * 64)

__global__ __launch_bounds__(256) void lconv_mix_kernel(
    const float* __restrict__ x, const float* __restrict__ wgt,
    float* __restrict__ out) {
  int idx = blockIdx.x * blockDim.x + threadIdx.x;  // N*32*64*64 = 262144
  int w  = idx & 63;
  int h  = (idx >> 6) & 63;
  int wc = (idx >> 12) & 31;
  int n  = idx >> 17;

  const float* wbase = wgt + (size_t)n * 1088 * HW_ + h * 64 + w;

  float w1[9];
  float w2[25];
#pragma unroll
  for (int t = 0; t < 9; ++t) w1[t] = wbase[(size_t)(wc * 9 + t) * HW_];
#pragma unroll
  for (int t = 0; t < 25; ++t) w2[t] = wbase[(size_t)(288 + wc * 25 + t) * HW_];

  const float* xn = x + (size_t)n * 256 * HW_;
  float* o1 = out + ((size_t)(n * 2 + 0) * 256) * HW_ + h * 64 + w;
  float* o2 = out + ((size_t)(n * 2 + 1) * 256) * HW_ + h * 64 + w;

#pragma unroll
  for (int g = 0; g < 8; ++g) {
    int cc = g * 32 + wc;
    const float* xc = xn + (size_t)cc * HW_;

    // Load 5x5 neighborhood (covers the 3x3 inner window too), zero-padded.
    float v[5][5];
#pragma unroll
    for (int i = 0; i < 5; ++i) {
      int hh = h + i - 2;
      bool hok = (hh >= 0) & (hh < 64);
#pragma unroll
      for (int j = 0; j < 5; ++j) {
        int ww = w + j - 2;
        bool ok = hok & (ww >= 0) & (ww < 64);
        v[i][j] = ok ? xc[hh * 64 + ww] : 0.0f;
      }
    }

    float a1 = 0.0f;
#pragma unroll
    for (int i = 0; i < 3; ++i)
#pragma unroll
      for (int j = 0; j < 3; ++j)
        a1 = fmaf(v[i + 1][j + 1], w1[i * 3 + j], a1);

    float a2 = 0.0f;
#pragma unroll
    for (int i = 0; i < 5; ++i)
#pragma unroll
      for (int j = 0; j < 5; ++j)
        a2 = fmaf(v[i][j], w2[i * 5 + j], a2);

    o1[(size_t)cc * HW_] = a1;
    o2[(size_t)cc * HW_] = a2;
  }
}

extern "C" void kernel_launch(void* const* d_in, const int* in_sizes, int n_in,
                              void* d_out, int out_size, void* d_ws,
                              size_t ws_size, hipStream_t stream) {
  const float* x = (const float*)d_in[0];
  const float* wgt = (const float*)d_in[1];
  float* out = (float*)d_out;

  int total = 2 * 32 * 64 * 64;  // N * WC * H * W
  dim3 block(256);
  dim3 grid(total / 256);
  lconv_mix_kernel<<<grid, block, 0, stream>>>(x, wgt, out);
}